// Round 15
// baseline (259.744 us; speedup 1.0000x reference)
//
#include <hip/hip_runtime.h>
#include <hip/hip_bf16.h>
#include <math.h>
#include <stdint.h>

// Round 15 == Round 14 resubmit (R14 bench was an infra acquisition timeout).
// GEMM K-loop software prefetch (A-tile one iter ahead, reg-dbuf, raw-fp32
// staging so cvt waits land at the write not the prefetch) + q/conv merged
// into one dispatch (conv first: heads critical path) + q/proj tiles 128x64.
// attn/LN/kv/preps unchanged from R13 (attn ~42us, out of top-5).

typedef float f32x4 __attribute__((ext_vector_type(4)));
typedef short bf16x8 __attribute__((ext_vector_type(8)));
typedef short bf16x4v __attribute__((ext_vector_type(4)));

#define QSCALE (0.17677669529663687f * 1.4426950408889634f)  // hd^-0.5 * log2(e)

__device__ inline unsigned short f2bf(float f) {
  __hip_bfloat16 h = __float2bfloat16(f);
  union { __hip_bfloat16 h; unsigned short u; } c;
  c.h = h;
  return c.u;
}

__device__ inline float fast_exp2(float x) {
#if __has_builtin(__builtin_amdgcn_exp2f)
  return __builtin_amdgcn_exp2f(x);
#else
  return __expf(x * 0.6931471805599453f);
#endif
}

// ---- prep kernels ----
__global__ __launch_bounds__(256) void prep_wT_all(
    const float* __restrict__ Wq, const float* __restrict__ Wp,
    const float* __restrict__ Wkv, unsigned short* __restrict__ WqT,
    unsigned short* __restrict__ WpT, unsigned short* __restrict__ WkvT) {
  int k = blockIdx.x, y = blockIdx.y, n = threadIdx.x;
  if (y == 0) {
    WqT[n * 256 + k] = f2bf(Wq[(size_t)k * 256 + n] * QSCALE);
  } else if (y == 1) {
    WpT[n * 256 + k] = f2bf(Wp[(size_t)k * 256 + n]);
  } else {
    int nn = (y - 2) * 256 + n;
    WkvT[nn * 256 + k] = f2bf(Wkv[(size_t)k * 512 + nn]);
  }
}

__global__ __launch_bounds__(256) void prep_srwT(const float* __restrict__ srw,
                                                 unsigned short* __restrict__ o) {
  int oc = blockIdx.x, t = threadIdx.x;
  const float* src = srw + (size_t)oc * 4096 + t * 16;
  f32x4 v[4];
#pragma unroll
  for (int j = 0; j < 4; ++j) v[j] = *(const f32x4*)(src + j * 4);
  unsigned short* dst = o + (size_t)oc * 4096 + t;
#pragma unroll
  for (int pp = 0; pp < 16; ++pp) dst[pp * 256] = f2bf(v[pp >> 2][pp & 3]);
}

// ---- bf16 MFMA GEMM body: C[M,N] = A[M,K_chunk] @ BT[N,K]^T (+bias) ----
// BK=64, 256 threads = 4 waves (2x2 over BM/2 x BN/2). NITER K-steps starting
// at kz*NITER*64. A-tile prefetched one iter ahead into regs (raw fp32 when
// AFP32 -- converted at LDS-write so the vmcnt wait lands there, not at the
// prefetch site). B loaded in-phase (small, L2-resident).
template <int BM, int BN, int NITER, int GATHER, int AFP32, int OUTBF, int BIAS>
__device__ __forceinline__ void gemm_body(
    const void* __restrict__ Av, const unsigned short* __restrict__ BT,
    const float* __restrict__ bias, void* __restrict__ Cout,
    int M, int N, int K, int bxi, int byi, int kz, char* smem) {
  constexpr int AISS = BM / 32, BISS = BN / 32;
  constexpr int WM = BM / 2, WN = BN / 2, FM = WM / 16, FN = WN / 16;
  unsigned short* As = (unsigned short*)smem;
  unsigned short* Bs = As + BM * 64;
  const int t = threadIdx.x;
  const int bm0 = bxi * BM, bn0 = byi * BN;
  const int k0b = kz * (NITER * 64);
  const int w = t >> 6, lane = t & 63, g = lane >> 4, li = lane & 15;
  const int wr = w >> 1, wc = w & 1;
  const int srow = t >> 3, scol = (t & 7) * 8;

  f32x4 acc[FM][FN];
#pragma unroll
  for (int mi = 0; mi < FM; ++mi)
#pragma unroll
    for (int ni = 0; ni < FN; ++ni) acc[mi][ni] = (f32x4){0.f, 0.f, 0.f, 0.f};

  f32x4 araw0[AISS][2], araw1[AISS][2];  // AFP32 staging (raw)
  bf16x8 areg0[AISS], areg1[AISS];       // bf16 staging

  auto aoff = [&](int j, int k0) -> size_t {
    int r = j * 32 + srow;
    if constexpr (GATHER) {
      int grow = bm0 + r;
      int bb = grow >> 8, rem = grow & 255;
      int oy = rem >> 4, ox = rem & 15;
      int kg = k0 + scol;
      int pos = kg >> 8, c = kg & 255;
      int ky = pos >> 2, kx = pos & 3;
      return ((size_t)(bb * 4096 + (4 * oy + ky) * 64 + 4 * ox + kx)) * 256 + c;
    } else {
      return (size_t)(bm0 + r) * K + k0 + scol;
    }
  };

  auto loadA = [&](int k0, f32x4 (*araw)[2], bf16x8* areg) {
#pragma unroll
    for (int j = 0; j < AISS; ++j) {
      size_t e = aoff(j, k0);
      if constexpr (AFP32) {
        const float* s = (const float*)Av + e;
        araw[j][0] = *(const f32x4*)s;
        araw[j][1] = *(const f32x4*)(s + 4);
      } else {
        areg[j] = *(const bf16x8*)((const unsigned short*)Av + e);
      }
    }
  };

  auto phase = [&](int k0, f32x4 (*araw)[2], bf16x8* areg,
                   int nk0, f32x4 (*nraw)[2], bf16x8* nareg, bool pf) {
    bf16x8 breg[BISS];
#pragma unroll
    for (int j = 0; j < BISS; ++j)
      breg[j] = *(const bf16x8*)(BT + (size_t)(bn0 + j * 32 + srow) * K + k0 + scol);
    __syncthreads();  // prev compute done before overwriting LDS
#pragma unroll
    for (int j = 0; j < AISS; ++j) {
      bf16x8 v;
      if constexpr (AFP32) {
#pragma unroll
        for (int e = 0; e < 4; ++e) {
          v[e] = (short)f2bf(araw[j][0][e]);
          v[e + 4] = (short)f2bf(araw[j][1][e]);
        }
      } else {
        v = areg[j];
      }
      *(bf16x8*)&As[(j * 32 + srow) * 64 + scol] = v;
    }
#pragma unroll
    for (int j = 0; j < BISS; ++j) *(bf16x8*)&Bs[(j * 32 + srow) * 64 + scol] = breg[j];
    __syncthreads();
    if (pf) loadA(nk0, nraw, nareg);  // prefetch: outstanding across compute
#pragma unroll
    for (int kc = 0; kc < 64; kc += 32) {
      bf16x8 af[FM], bfr[FN];
#pragma unroll
      for (int mi = 0; mi < FM; ++mi)
        af[mi] = *(const bf16x8*)&As[(wr * WM + mi * 16 + li) * 64 + kc + g * 8];
#pragma unroll
      for (int ni = 0; ni < FN; ++ni)
        bfr[ni] = *(const bf16x8*)&Bs[(wc * WN + ni * 16 + li) * 64 + kc + g * 8];
#pragma unroll
      for (int mi = 0; mi < FM; ++mi)
#pragma unroll
        for (int ni = 0; ni < FN; ++ni)
          acc[mi][ni] = __builtin_amdgcn_mfma_f32_16x16x32_bf16(af[mi], bfr[ni],
                                                               acc[mi][ni], 0, 0, 0);
    }
  };

  loadA(k0b, araw0, areg0);
#pragma unroll
  for (int i = 0; i < NITER; i += 2) {
    phase(k0b + i * 64, araw0, areg0, k0b + (i + 1) * 64, araw1, areg1, i + 1 < NITER);
    phase(k0b + (i + 1) * 64, araw1, areg1, k0b + (i + 2) * 64, araw0, areg0,
          i + 2 < NITER);
  }

#pragma unroll
  for (int mi = 0; mi < FM; ++mi) {
    int row = bm0 + wr * WM + mi * 16 + 4 * g;
#pragma unroll
    for (int ni = 0; ni < FN; ++ni) {
      int col = bn0 + wc * WN + ni * 16 + li;
      f32x4 v = acc[mi][ni];
      if constexpr (BIAS) {
        float bb = bias[col];
        v[0] += bb; v[1] += bb; v[2] += bb; v[3] += bb;
      }
      if constexpr (OUTBF) {
        unsigned short* C = (unsigned short*)Cout + (size_t)kz * M * N;
#pragma unroll
        for (int r = 0; r < 4; ++r) C[(size_t)(row + r) * N + col] = f2bf(v[r]);
      } else {
        float* C = (float*)Cout + (size_t)kz * M * N;
#pragma unroll
        for (int r = 0; r < 4; ++r) C[(size_t)(row + r) * N + col] = v[r];
      }
    }
  }
}

template <int BM, int BN, int NITER, int GATHER, int AFP32, int OUTBF, int BIAS>
__global__ __launch_bounds__(256) void gemm_bf16(
    const void* __restrict__ Av, const unsigned short* __restrict__ BT,
    const float* __restrict__ bias, void* __restrict__ Cout, int M, int N, int K) {
  extern __shared__ char smem[];
  gemm_body<BM, BN, NITER, GATHER, AFP32, OUTBF, BIAS>(
      Av, BT, bias, Cout, M, N, K, blockIdx.x, blockIdx.y, blockIdx.z, smem);
}

// Merged conv + q dispatch. conv blocks first (critical path conv->LN->kv).
// conv: 64 x-tiles x 4 n-tiles x 4 kz = 1024 blocks (BM=BN=64, NITER=16).
// q:    512 m-tiles x 4 n-tiles      = 2048 blocks (BM=128, BN=64, NITER=4).
__global__ __launch_bounds__(256) void qconv_kernel(
    const float* __restrict__ x, const unsigned short* __restrict__ wqT,
    const unsigned short* __restrict__ srwT, unsigned short* __restrict__ qbf,
    float* __restrict__ xrp) {
  extern __shared__ char smem[];
  int bid = blockIdx.x;
  if (bid < 1024) {
    gemm_body<64, 64, 16, 1, 1, 0, 0>(x, srwT, nullptr, xrp, 4096, 256, 4096,
                                      bid & 63, (bid >> 6) & 3, bid >> 8, smem);
  } else {
    int r = bid - 1024;
    gemm_body<128, 64, 4, 0, 1, 1, 0>(x, wqT, nullptr, qbf, 65536, 256, 256,
                                      r >> 2, r & 3, 0, smem);
  }
}

// ---- LayerNorm over 4 split-K partials + bias, bf16 out ----
__global__ __launch_bounds__(256) void ln4_kernel(const float* __restrict__ xrp,
                                                  const float* __restrict__ srb,
                                                  const float* __restrict__ g,
                                                  const float* __restrict__ bta,
                                                  unsigned short* __restrict__ out) {
  const int row = blockIdx.x * 4 + (threadIdx.x >> 6);
  const int lane = threadIdx.x & 63;
  const size_t off = (size_t)row * 256 + lane * 4;
  const size_t CH = (size_t)4096 * 256;
  f32x4 v = *(const f32x4*)(xrp + off);
  v += *(const f32x4*)(xrp + CH + off);
  v += *(const f32x4*)(xrp + 2 * CH + off);
  v += *(const f32x4*)(xrp + 3 * CH + off);
  v += *(const f32x4*)&srb[lane * 4];
  float s = v[0] + v[1] + v[2] + v[3];
  float sq = v[0] * v[0] + v[1] * v[1] + v[2] * v[2] + v[3] * v[3];
#pragma unroll
  for (int o = 32; o > 0; o >>= 1) {
    s += __shfl_xor(s, o);
    sq += __shfl_xor(sq, o);
  }
  float mean = s * (1.0f / 256.0f);
  float var = sq * (1.0f / 256.0f) - mean * mean;
  float rstd = rsqrtf(var + 1e-5f);
  f32x4 gv = *(const f32x4*)&g[lane * 4];
  f32x4 bv = *(const f32x4*)&bta[lane * 4];
  bf16x4v o;
#pragma unroll
  for (int j = 0; j < 4; ++j) o[j] = (short)f2bf((v[j] - mean) * rstd * gv[j] + bv[j]);
  *(bf16x4v*)&out[(size_t)row * 256 + lane * 4] = o;
}

// ---- MFMA attention (unchanged from R13: no-max softmax + tree-sum) ----
__global__ __launch_bounds__(256) void attn_mfma(const unsigned short* __restrict__ qbf,
                                                 const unsigned short* __restrict__ kvbf,
                                                 unsigned short* __restrict__ obf) {
  __shared__ unsigned short Ks[256 * 40];
  __shared__ unsigned short Vt2[32 * 264];
  const int t = threadIdx.x;
  const int idx = blockIdx.x;
  const int bh = idx >> 4, nblk = idx & 15;
  const int b = bh >> 3, h = bh & 7;
  {
    const unsigned short* kp = kvbf + ((size_t)(b * 256 + t)) * 512 + h * 32;
    bf16x8 kr[4], vr[4];
#pragma unroll
    for (int j = 0; j < 4; ++j) kr[j] = *(const bf16x8*)(kp + j * 8);
#pragma unroll
    for (int j = 0; j < 4; ++j) vr[j] = *(const bf16x8*)(kp + 256 + j * 8);
#pragma unroll
    for (int j = 0; j < 4; ++j) *(bf16x8*)&Ks[t * 40 + j * 8] = kr[j];
    const int m = t;
    const int pcol = (m & ~31) + ((m >> 2) & 3) * 8 + (m & 3) + 4 * ((m >> 4) & 1);
#pragma unroll
    for (int j = 0; j < 4; ++j)
#pragma unroll
      for (int e = 0; e < 8; ++e) Vt2[(j * 8 + e) * 264 + pcol] = (unsigned short)vr[j][e];
  }
  __syncthreads();
  const int w = t >> 6, lane = t & 63, g = lane >> 4, li = lane & 15;
  const int nbase = nblk * 256 + w * 64;
#pragma unroll 1
  for (int nt = 0; nt < 4; ++nt) {
    const int nrow = nbase + nt * 16 + li;
    bf16x8 qf = *(const bf16x8*)(qbf + ((size_t)(b * 4096 + nrow)) * 256 + h * 32 + g * 8);
    f32x4 zero = {0.f, 0.f, 0.f, 0.f};
    f32x4 st[16];
    float sm[16];
#pragma unroll
    for (int mt = 0; mt < 16; ++mt) {
      bf16x8 kf = *(const bf16x8*)&Ks[(mt * 16 + li) * 40 + g * 8];
      st[mt] = __builtin_amdgcn_mfma_f32_16x16x32_bf16(kf, qf, zero, 0, 0, 0);
    }
#pragma unroll
    for (int mt = 0; mt < 16; ++mt) {
      f32x4 p;
#pragma unroll
      for (int r = 0; r < 4; ++r) p[r] = fast_exp2(st[mt][r]);
      st[mt] = p;
      sm[mt] = (p[0] + p[1]) + (p[2] + p[3]);
    }
#pragma unroll
    for (int s = 8; s > 0; s >>= 1)
#pragma unroll
      for (int i = 0; i < 8; ++i)
        if (i < s) sm[i] += sm[i + s];
    float l = sm[0];
    l += __shfl_xor(l, 16);
    l += __shfl_xor(l, 32);
    const float rl = 1.0f / l;
    bf16x8 pb[8];
#pragma unroll
    for (int c = 0; c < 8; ++c)
#pragma unroll
      for (int e = 0; e < 4; ++e) {
        pb[c][e] = (short)f2bf(st[2 * c][e]);
        pb[c][e + 4] = (short)f2bf(st[2 * c + 1][e]);
      }
#pragma unroll
    for (int dt = 0; dt < 2; ++dt) {
      f32x4 acc = {0.f, 0.f, 0.f, 0.f};
      const int drow = (dt * 16 + li) * 264;
#pragma unroll
      for (int c = 0; c < 8; ++c) {
        bf16x8 vf = *(const bf16x8*)&Vt2[drow + c * 32 + g * 8];
        acc = __builtin_amdgcn_mfma_f32_16x16x32_bf16(vf, pb[c], acc, 0, 0, 0);
      }
      unsigned short* op = obf + ((size_t)(b * 4096 + nbase + nt * 16 + li)) * 256 +
                           h * 32 + dt * 16 + 4 * g;
      bf16x4v ov;
#pragma unroll
      for (int r = 0; r < 4; ++r) ov[r] = (short)f2bf(acc[r] * rl);
      *(bf16x4v*)op = ov;
    }
  }
}

extern "C" void kernel_launch(void* const* d_in, const int* in_sizes, int n_in,
                              void* d_out, int out_size, void* d_ws, size_t ws_size,
                              hipStream_t stream) {
  const float* x   = (const float*)d_in[0];
  const float* Wq  = (const float*)d_in[1];
  const float* Wkv = (const float*)d_in[2];
  const float* srw = (const float*)d_in[3];
  const float* srb = (const float*)d_in[4];
  const float* lng = (const float*)d_in[5];
  const float* lnb = (const float*)d_in[6];
  const float* Wp  = (const float*)d_in[7];
  const float* bp  = (const float*)d_in[8];
  float* out = (float*)d_out;

  char* wsc = (char*)d_ws;
  unsigned short* qbf   = (unsigned short*)(wsc);              // 33.5 MB
  unsigned short* abf   = (unsigned short*)(wsc + 33554432);   // 33.5 MB
  float*          xrp   = (float*)(wsc + 67108864);            // 16.8 MB (4 chunks)
  unsigned short* xlnbf = (unsigned short*)(wsc + 83886080);   // 2.1 MB
  unsigned short* kvb   = (unsigned short*)(wsc + 85983232);   // 4.2 MB
  unsigned short* wqT   = (unsigned short*)(wsc + 90177536);   // 128 KB
  unsigned short* wpT   = (unsigned short*)(wsc + 90308608);   // 128 KB
  unsigned short* wkvT  = (unsigned short*)(wsc + 90439680);   // 256 KB
  unsigned short* srwT  = (unsigned short*)(wsc + 90701824);   // 2.1 MB

  prep_wT_all<<<dim3(256, 4), 256, 0, stream>>>(Wq, Wp, Wkv, wqT, wpT, wkvT);
  prep_srwT<<<256, 256, 0, stream>>>(srw, srwT);
  // conv partials (split-K x4, fp32) + q = x @ (Wq*QSCALE) in ONE dispatch
  qconv_kernel<<<3072, 256, 24576, stream>>>(x, wqT, srwT, qbf, xrp);
  // xln = LN(sum partials + srb)  (bf16 out)
  ln4_kernel<<<1024, 256, 0, stream>>>(xrp, srb, lng, lnb, xlnbf);
  // kv = xln @ Wkv  (bf16 MFMA, bf16 out)
  gemm_bf16<64, 64, 4, 0, 0, 1, 0><<<dim3(64, 8), 256, 16384, stream>>>(
      xlnbf, wkvT, nullptr, kvb, 4096, 512, 256);
  attn_mfma<<<2048, 256, 0, stream>>>(qbf, kvb, abf);
  // out = attn @ Wp + bp  (bf16 A, fp32 out)
  gemm_bf16<128, 64, 4, 0, 0, 0, 1><<<dim3(512, 4), 256, 24576, stream>>>(
      abf, wpT, bp, out, 65536, 256, 256);
}